// Round 24
// baseline (338.057 us; speedup 1.0000x reference)
//
#include <hip/hip_runtime.h>
#include <stdint.h>

typedef unsigned short ushort_t;
typedef short bf16x4 __attribute__((ext_vector_type(4)));
typedef short bf16x8 __attribute__((ext_vector_type(8)));
typedef float f32x4 __attribute__((ext_vector_type(4)));
typedef float f32x16 __attribute__((ext_vector_type(16)));
typedef float f32x4v __attribute__((ext_vector_type(4)));

// ---------- helpers ----------
__device__ __forceinline__ ushort_t f2bf(float f) {
  unsigned int u = __builtin_bit_cast(unsigned int, f);
  u += 0x7fffu + ((u >> 16) & 1u);
  return (ushort_t)(u >> 16);
}
__device__ __forceinline__ float bf2f(ushort_t h) {
  unsigned int u = ((unsigned int)h) << 16;
  return __builtin_bit_cast(float, u);
}
__device__ __forceinline__ float exp2_hw(float x) {
  return __builtin_amdgcn_exp2f(x);  // v_exp_f32: D = 2^S0
}
__device__ __forceinline__ void load_lds16(const void* g, void* l) {
  __builtin_amdgcn_global_load_lds(
      (const __attribute__((address_space(1))) void*)g,
      (__attribute__((address_space(3))) void*)l, 16, 0, 0);
}

// ---------- x fp32 -> bf16 (fallback path) ----------
__global__ __launch_bounds__(256) void cvt_x_kernel(const float* __restrict__ x,
                                                    ushort_t* __restrict__ xb) {
  int i = blockIdx.x * 256 + threadIdx.x;  // each thread: 8 elems
  const f32x4v* xv = (const f32x4v*)x;
  f32x4v a = xv[2 * i], b = xv[2 * i + 1];
  bf16x8 o;
  o[0] = (short)f2bf(a[0]); o[1] = (short)f2bf(a[1]);
  o[2] = (short)f2bf(a[2]); o[3] = (short)f2bf(a[3]);
  o[4] = (short)f2bf(b[0]); o[5] = (short)f2bf(b[1]);
  o[6] = (short)f2bf(b[2]); o[7] = (short)f2bf(b[3]);
  ((bf16x8*)xb)[i] = o;
}

// ---------- weight fp32 [R][C] -> bf16 transposed [C][R], vectorized (fallback) ----------
__global__ __launch_bounds__(256) void tr_cvt_kernel(const float* __restrict__ src,
                                                     ushort_t* __restrict__ dst,
                                                     int R, int C) {
  __shared__ float tile[64][65];
  int r0 = blockIdx.y * 64, c0 = blockIdx.x * 64;
  int t = threadIdx.x;
#pragma unroll
  for (int i = 0; i < 4; i++) {
    int idx = t + i * 256;          // 0..1023
    int r = idx >> 4, c4 = idx & 15;
    f32x4v v = *(const f32x4v*)&src[(size_t)(r0 + r) * C + c0 + c4 * 4];
#pragma unroll
    for (int j = 0; j < 4; j++) tile[r][c4 * 4 + j] = v[j];
  }
  __syncthreads();
#pragma unroll
  for (int i = 0; i < 4; i++) {
    int idx = t + i * 256;
    int cr = idx >> 4, cg = idx & 15;
    bf16x4 o;
#pragma unroll
    for (int j = 0; j < 4; j++) o[j] = (short)f2bf(tile[cg * 4 + j][cr]);
    *(bf16x4*)&dst[(size_t)(c0 + cr) * R + r0 + cg * 4] = o;
  }
}

// ---------- consolidated prep: cvt_x + 4 weight transposes (verified R23) ----------
__global__ __launch_bounds__(256) void prepw_kernel(const float* __restrict__ x,
                                                    const float* __restrict__ wq,
                                                    const float* __restrict__ wk,
                                                    const float* __restrict__ wv,
                                                    const float* __restrict__ wo,
                                                    ushort_t* __restrict__ xb,
                                                    ushort_t* __restrict__ wT,
                                                    ushort_t* __restrict__ woT) {
  __shared__ float tile[64][65];
  const int id = blockIdx.x;
  const int t = threadIdx.x;
  if (id < 4096) {
    int i = id * 256 + t;
    const f32x4v* xv = (const f32x4v*)x;
    f32x4v a = xv[2 * i], b = xv[2 * i + 1];
    bf16x8 o;
    o[0] = (short)f2bf(a[0]); o[1] = (short)f2bf(a[1]);
    o[2] = (short)f2bf(a[2]); o[3] = (short)f2bf(a[3]);
    o[4] = (short)f2bf(b[0]); o[5] = (short)f2bf(b[1]);
    o[6] = (short)f2bf(b[2]); o[7] = (short)f2bf(b[3]);
    ((bf16x8*)xb)[i] = o;
    return;
  }
  const float* src;
  ushort_t* dst;
  int C, r0, c0;
  if (id < 8192) {
    int q = id - 4096; src = wq; dst = wT; C = 4096;
    c0 = (q & 63) * 64; r0 = (q >> 6) * 64;
  } else if (id < 9216) {
    int q = id - 8192; src = wk; dst = wT + (size_t)4096 * 4096; C = 1024;
    c0 = (q & 15) * 64; r0 = (q >> 4) * 64;
  } else if (id < 10240) {
    int q = id - 9216; src = wv; dst = wT + (size_t)5120 * 4096; C = 1024;
    c0 = (q & 15) * 64; r0 = (q >> 4) * 64;
  } else {
    int q = id - 10240; src = wo; dst = woT; C = 4096;
    c0 = (q & 63) * 64; r0 = (q >> 6) * 64;
  }
  const int R = 4096;
#pragma unroll
  for (int i = 0; i < 4; i++) {
    int idx = t + i * 256;
    int r = idx >> 4, c4 = idx & 15;
    f32x4v v = *(const f32x4v*)&src[(size_t)(r0 + r) * C + c0 + c4 * 4];
#pragma unroll
    for (int j = 0; j < 4; j++) tile[r][c4 * 4 + j] = v[j];
  }
  __syncthreads();
#pragma unroll
  for (int i = 0; i < 4; i++) {
    int idx = t + i * 256;
    int cr = idx >> 4, cg = idx & 15;
    bf16x4 o;
#pragma unroll
    for (int j = 0; j < 4; j++) o[j] = (short)f2bf(tile[cg * 4 + j][cr]);
    *(bf16x4*)&dst[(size_t)(c0 + cr) * R + r0 + cg * 4] = o;
  }
}

// ---------- RoPE in-place on C1 (fallback path) ----------
__global__ __launch_bounds__(256) void rope_kernel(ushort_t* __restrict__ C1,
                                                   const float* __restrict__ cosb,
                                                   const float* __restrict__ sinb) {
  int idx = blockIdx.x * 256 + threadIdx.x;  // 2048 * 640
  int s = idx / 640;
  int col0 = (idx % 640) * 8;
  int i0 = (col0 & 127) >> 1;
  const float qs = (col0 < 4096) ? 0.12753055296570565f : 1.0f;  // scale*log2e
  ushort_t* p = C1 + (size_t)s * 6144 + col0;
  bf16x8 v = *(const bf16x8*)p;
  bf16x8 o;
  const float* cr = cosb + s * 64 + i0;
  const float* sr = sinb + s * 64 + i0;
#pragma unroll
  for (int j = 0; j < 4; j++) {
    float tr = bf2f((ushort_t)v[2 * j]);
    float ti = bf2f((ushort_t)v[2 * j + 1]);
    float c = cr[j], sn = sr[j];
    o[2 * j] = (short)f2bf((tr * c - ti * sn) * qs);
    o[2 * j + 1] = (short)f2bf((tr * sn + ti * c) * qs);
  }
  *(bf16x8*)p = o;
}

// ---------- V part of C1 -> VT [1024][2048] (row = hk*128+d, col = s) ----------
__global__ __launch_bounds__(256) void trv_kernel(const ushort_t* __restrict__ C1,
                                                  ushort_t* __restrict__ VT) {
  __shared__ ushort_t tile[64][65];
  int c0 = blockIdx.x * 64;  // within 1024
  int r0 = blockIdx.y * 64;  // within 2048
  int t = threadIdx.x;
#pragma unroll
  for (int i = 0; i < 16; i++) {
    int idx = t + i * 256;
    int r = idx >> 6, c = idx & 63;
    tile[r][c] = C1[(size_t)(r0 + r) * 6144 + 5120 + c0 + c];
  }
  __syncthreads();
#pragma unroll
  for (int i = 0; i < 16; i++) {
    int idx = t + i * 256;
    int cr = idx >> 6, cc = idx & 63;
    VT[(size_t)(c0 + cr) * 2048 + r0 + cc] = tile[cc][cr];
  }
}

// ---------- 2D-chunked XCD block mapping ----------
__device__ __forceinline__ void xcd_chunk_map(int id, int nby, int nbx,
                                              int& browi, int& bcoli) {
  const int xcd = id & 7;
  const int j = id >> 3;
  const int rch = nby >> 1, cch = nbx >> 2;  // chunk dims
  const int cr = xcd >> 2, cc = xcd & 3;     // chunk grid is 2 x 4
  const int r = j / cch, c = j % cch;
  browi = cr * rch + r;
  bcoli = cc * cch + c;
}

// ---------- GEMM 256x192, 1-phase/64-K (gemm1/QKV; verified R22) ----------
template <typename OutT>
__global__ __launch_bounds__(512) void gemmC_kernel(const ushort_t* __restrict__ A,
                                                    const ushort_t* __restrict__ BT,
                                                    OutT* __restrict__ C,
                                                    int M, int N, int K, int ldc) {
  __shared__ ushort_t As[2][256 * 64];  // 64KB
  __shared__ ushort_t Bs[3][192 * 64];  // 72KB
  const int nbx = N / 192, nby = M >> 8;
  int browi, bcoli;
  xcd_chunk_map((int)blockIdx.x, nby, nbx, browi, bcoli);
  const int brow = browi << 8, bcol = bcoli * 192;
  const int tid = threadIdx.x, w = tid >> 6, lane = tid & 63;
  const int wr = w >> 2, wc = w & 3;
  const int lr = lane & 15, lk = lane >> 4;

  const ushort_t* Ab = A + (size_t)brow * K;
  const ushort_t* Bb = BT + (size_t)bcol * K;

  auto stageQ = [&](const ushort_t* gbase, char* lds, int t, int q) {
    int L = q * 512 + tid;
    int r = L >> 3, sc = L & 7;
    load_lds16(gbase + (size_t)r * K + (t << 6) + ((sc ^ (r & 7)) << 3), lds + L * 16);
  };

  f32x4 acc[8][3] = {};
  const int NT = K >> 6;  // requires NT >= 3

  // prologue: B(0)x3, A(0)q0,q2,q1,q3, B(1)x3; drain through A(0)q3 -> vmcnt(3)
#pragma unroll
  for (int q = 0; q < 3; ++q) stageQ(Bb, (char*)&Bs[0][0], 0, q);
  stageQ(Ab, (char*)&As[0][0], 0, 0);
  stageQ(Ab, (char*)&As[0][0], 0, 2);
  stageQ(Ab, (char*)&As[0][0], 0, 1);
  stageQ(Ab, (char*)&As[0][0], 0, 3);
#pragma unroll
  for (int q = 0; q < 3; ++q) stageQ(Bb, (char*)&Bs[1][0], 1, q);
  asm volatile("s_waitcnt vmcnt(3)" ::: "memory");
  __builtin_amdgcn_s_barrier();

  int bcur = 0;
  for (int t = 0; t < NT; ++t) {
    const int c = t & 1;
    const char* Ac = (const char*)&As[c][0];
    const char* Bc = (const char*)&Bs[bcur][0];
    char* An = (char*)&As[c ^ 1][0];
    const int bnxt = (bcur + 2 >= 3) ? bcur - 1 : bcur + 2;  // (t+2)%3
    char* Bn = (char*)&Bs[bnxt][0];
    const bool pfA = (t + 1 < NT), pfB = (t + 2 < NT);

    bf16x8 af[8][2], bfr[3][2];
#pragma unroll
    for (int mm = 0; mm < 8; ++mm)
#pragma unroll
      for (int ks = 0; ks < 2; ++ks) {
        int rA = wr * 128 + mm * 16 + lr;
        af[mm][ks] = *(const bf16x8*)(Ac + rA * 128 + (((ks * 4 + lk) ^ (rA & 7)) << 4));
      }
#pragma unroll
    for (int n = 0; n < 3; ++n)
#pragma unroll
      for (int ks = 0; ks < 2; ++ks) {
        int rB = wc * 48 + n * 16 + lr;
        bfr[n][ks] = *(const bf16x8*)(Bc + rB * 128 + (((ks * 4 + lk) ^ (rB & 7)) << 4));
      }
    if (pfA) {
      stageQ(Ab, An, t + 1, 0); stageQ(Ab, An, t + 1, 2);
      stageQ(Ab, An, t + 1, 1); stageQ(Ab, An, t + 1, 3);
    }
    if (pfB) { stageQ(Bb, Bn, t + 2, 0); stageQ(Bb, Bn, t + 2, 1); stageQ(Bb, Bn, t + 2, 2); }
    __builtin_amdgcn_s_barrier();
    asm volatile("s_waitcnt lgkmcnt(0)" ::: "memory");
    __builtin_amdgcn_sched_barrier(0);
    __builtin_amdgcn_s_setprio(1);
#pragma unroll
    for (int mm = 0; mm < 8; ++mm)
#pragma unroll
      for (int n = 0; n < 3; ++n)
#pragma unroll
        for (int ks = 0; ks < 2; ++ks)
          acc[mm][n] = __builtin_amdgcn_mfma_f32_16x16x32_bf16(af[mm][ks], bfr[n][ks],
                                                               acc[mm][n], 0, 0, 0);
    __builtin_amdgcn_s_setprio(0);
    if (pfB)
      asm volatile("s_waitcnt vmcnt(3)" ::: "memory");  // A(t+1)+B(t+1) landed
    else if (pfA)
      asm volatile("s_waitcnt vmcnt(0)" ::: "memory");  // tail drain
    __builtin_amdgcn_s_barrier();
    bcur = (bcur + 1 == 3) ? 0 : bcur + 1;
  }
  // epilogue
#pragma unroll
  for (int m = 0; m < 8; ++m)
#pragma unroll
    for (int n = 0; n < 3; ++n) {
      int row = brow + wr * 128 + m * 16 + lk * 4;
      int col = bcol + wc * 48 + n * 16 + lr;
#pragma unroll
      for (int j = 0; j < 4; ++j) {
        float v = acc[m][n][j];
        if constexpr (sizeof(OutT) == 2)
          C[(size_t)(row + j) * ldc + col] = (OutT)f2bf(v);
        else
          C[(size_t)(row + j) * ldc + col] = v;
      }
    }
}

// ---------- GEMM 256x128, 1-phase/64-K (gemm2; verified R22) ----------
template <typename OutT>
__global__ __launch_bounds__(512) void gemmD_kernel(const ushort_t* __restrict__ A,
                                                    const ushort_t* __restrict__ BT,
                                                    OutT* __restrict__ C,
                                                    int M, int N, int K, int ldc) {
  __shared__ ushort_t As[3][256 * 64];  // 96KB
  __shared__ ushort_t Bs[3][128 * 64];  // 48KB
  const int nbx = N >> 7, nby = M >> 8;
  int browi, bcoli;
  xcd_chunk_map((int)blockIdx.x, nby, nbx, browi, bcoli);
  const int brow = browi << 8, bcol = bcoli << 7;
  const int tid = threadIdx.x, w = tid >> 6, lane = tid & 63;
  const int wr = w >> 2, wc = w & 3;
  const int lr = lane & 15, lk = lane >> 4;

  const ushort_t* Ab = A + (size_t)brow * K;
  const ushort_t* Bb = BT + (size_t)bcol * K;

  auto stageQ = [&](const ushort_t* gbase, char* lds, int t, int q) {
    int L = q * 512 + tid;
    int r = L >> 3, sc = L & 7;
    load_lds16(gbase + (size_t)r * K + (t << 6) + ((sc ^ (r & 7)) << 3), lds + L * 16);
  };
  auto stageTile = [&](int t, int buf) {  // 6 loads: A q0..q3 + B q0,q1
#pragma unroll
    for (int q = 0; q < 4; ++q) stageQ(Ab, (char*)&As[buf][0], t, q);
#pragma unroll
    for (int q = 0; q < 2; ++q) stageQ(Bb, (char*)&Bs[buf][0], t, q);
  };

  f32x4 acc[8][2] = {};
  const int NT = K >> 6;

  stageTile(0, 0);
  stageTile(1, 1);
  asm volatile("s_waitcnt vmcnt(6)" ::: "memory");
  __builtin_amdgcn_s_barrier();

  int cur = 0;
  for (int t = 0; t < NT; ++t) {
    const char* Ac = (const char*)&As[cur][0];
    const char* Bc = (const char*)&Bs[cur][0];
    const int nxt = (cur + 2 >= 3) ? cur - 1 : cur + 2;  // (t+2)%3
    const bool pf = (t + 2 < NT);

    bf16x8 af[8][2], bfr[2][2];
#pragma unroll
    for (int mm = 0; mm < 8; ++mm)
#pragma unroll
      for (int ks = 0; ks < 2; ++ks) {
        int rA = wr * 128 + mm * 16 + lr;
        af[mm][ks] = *(const bf16x8*)(Ac + rA * 128 + (((ks * 4 + lk) ^ (rA & 7)) << 4));
      }
#pragma unroll
    for (int n = 0; n < 2; ++n)
#pragma unroll
      for (int ks = 0; ks < 2; ++ks) {
        int rB = wc * 32 + n * 16 + lr;
        bfr[n][ks] = *(const bf16x8*)(Bc + rB * 128 + (((ks * 4 + lk) ^ (rB & 7)) << 4));
      }
    if (pf) stageTile(t + 2, nxt);
    __builtin_amdgcn_s_barrier();
    asm volatile("s_waitcnt lgkmcnt(0)" ::: "memory");
    __builtin_amdgcn_sched_barrier(0);
    __builtin_amdgcn_s_setprio(1);
#pragma unroll
    for (int mm = 0; mm < 8; ++mm)
#pragma unroll
      for (int n = 0; n < 2; ++n)
#pragma unroll
        for (int ks = 0; ks < 2; ++ks)
          acc[mm][n] = __builtin_amdgcn_mfma_f32_16x16x32_bf16(af[mm][ks], bfr[n][ks],
                                                               acc[mm][n], 0, 0, 0);
    __builtin_amdgcn_s_setprio(0);
    if (pf)
      asm volatile("s_waitcnt vmcnt(6)" ::: "memory");  // t+1 landed; t+2 in flight
    else if (t + 1 < NT)
      asm volatile("s_waitcnt vmcnt(0)" ::: "memory");  // tail drain
    __builtin_amdgcn_s_barrier();
    cur = (cur == 2) ? 0 : cur + 1;
  }
  // epilogue
#pragma unroll
  for (int m = 0; m < 8; ++m)
#pragma unroll
    for (int n = 0; n < 2; ++n) {
      int row = brow + wr * 128 + m * 16 + lk * 4;
      int col = bcol + wc * 32 + n * 16 + lr;
#pragma unroll
      for (int j = 0; j < 4; ++j) {
        float v = acc[m][n][j];
        if constexpr (sizeof(OutT) == 2)
          C[(size_t)(row + j) * ldc + col] = (OutT)f2bf(v);
        else
          C[(size_t)(row + j) * ldc + col] = v;
      }
    }
}

// ---------- GEMM: C[M][ldc] = A[M][K] * BT[N][K]^T  (m97 structure, fallback) ----------
template <typename OutT>
__global__ __launch_bounds__(256) void gemm128_kernel(const ushort_t* __restrict__ A,
                                                      const ushort_t* __restrict__ BT,
                                                      OutT* __restrict__ C,
                                                      int M, int N, int K, int ldc) {
  __shared__ ushort_t As[128 * 32];
  __shared__ ushort_t Bs[128 * 32];
  int brow = blockIdx.y * 128, bcol = blockIdx.x * 128;
  int tid = threadIdx.x, w = tid >> 6, lane = tid & 63;
  int wr = w >> 1, wc = w & 1;
  int lr = lane & 15, lk = lane >> 4;
  f32x4 acc[4][4] = {};

  int srow = lane >> 2;
  int scol = (lane & 3) * 8;
  const ushort_t* Ab = A + (size_t)brow * K + scol;
  const ushort_t* Bb = BT + (size_t)bcol * K + scol;

  for (int kt = 0; kt < K; kt += 32) {
#pragma unroll
    for (int i = 0; i < 2; i++) {
      int seg = w * 2 + i;
      int row = seg * 16 + srow;
      load_lds16(Ab + (size_t)row * K + kt, (char*)As + seg * 1024);
      load_lds16(Bb + (size_t)row * K + kt, (char*)Bs + seg * 1024);
    }
    __syncthreads();
    bf16x8 af[4], bfr[4];
#pragma unroll
    for (int m = 0; m < 4; m++)
      af[m] = *(const bf16x8*)&As[(wr * 64 + m * 16 + lr) * 32 + lk * 8];
#pragma unroll
    for (int n = 0; n < 4; n++)
      bfr[n] = *(const bf16x8*)&Bs[(wc * 64 + n * 16 + lr) * 32 + lk * 8];
#pragma unroll
    for (int m = 0; m < 4; m++)
#pragma unroll
      for (int n = 0; n < 4; n++)
        acc[m][n] = __builtin_amdgcn_mfma_f32_16x16x32_bf16(af[m], bfr[n], acc[m][n], 0, 0, 0);
    __syncthreads();
  }
#pragma unroll
  for (int m = 0; m < 4; m++)
#pragma unroll
    for (int n = 0; n < 4; n++) {
      int row = brow + wr * 64 + m * 16 + lk * 4;
      int col = bcol + wc * 64 + n * 16 + lr;
#pragma unroll
      for (int j = 0; j < 4; j++) {
        float v = acc[m][n][j];
        if constexpr (sizeof(OutT) == 2)
          C[(size_t)(row + j) * ldc + col] = (OutT)f2bf(v);
        else
          C[(size_t)(row + j) * ldc + col] = v;
      }
    }
}

// ---------- gemmS v3: fused RoPE staging + exp2(Q K^T) causal, K=128 ----------
// Reg-staged: each thread loads 16B chunks of un-roped Q/K from C1 (linear),
// applies RoPE in-register (chunk s holds 4 complete rope pairs; cos/sin at
// [srow*64 + s*4..+3] is one f32x4 — same indexing as verified rope_kernel;
// Q additionally scaled by 1/sqrt(128)*log2e), then ds_write_b128 to the
// swizzled position p=(s&8)|((s&7)^(r&7)) that the verified fragment readers
// expect. Eliminates the standalone rope dispatch + its 40MB round trip.
__global__ __launch_bounds__(256) void gemmS_kernel(const ushort_t* __restrict__ C1,
                                                    ushort_t* __restrict__ P,
                                                    const float* __restrict__ cosb,
                                                    const float* __restrict__ sinb) {
  int rem = blockIdx.x, rt = 0;
  while (rem > rt) { rem -= (rt + 1); rt++; }
  const int ct = rem;
  const int h = blockIdx.y, hk = h >> 2;

  __shared__ ushort_t As_[128 * 128];  // 32KB
  __shared__ ushort_t Bs_[128 * 128];  // 32KB
  const int tid = threadIdx.x, w = tid >> 6, lane = tid & 63;
  const int wr = w >> 1, wc = w & 1;
  const int lr = lane & 15, lk = lane >> 4;
  const float QS = 0.12753055296570565f;  // 1/sqrt(128)*log2e

  // stage A (Q rows rt*128.., head h) with rope*QS
#pragma unroll
  for (int i = 0; i < 8; ++i) {
    int L = i * 256 + tid;          // 0..2047
    int r = L >> 4, s = L & 15;
    int srow = rt * 128 + r;
    bf16x8 v = *(const bf16x8*)(C1 + (size_t)srow * 6144 + h * 128 + s * 8);
    f32x4v cv = *(const f32x4v*)&cosb[srow * 64 + s * 4];
    f32x4v sv = *(const f32x4v*)&sinb[srow * 64 + s * 4];
    bf16x8 o;
#pragma unroll
    for (int j = 0; j < 4; ++j) {
      float tr = bf2f((ushort_t)v[2 * j]);
      float ti = bf2f((ushort_t)v[2 * j + 1]);
      o[2 * j] = (short)f2bf((tr * cv[j] - ti * sv[j]) * QS);
      o[2 * j + 1] = (short)f2bf((tr * sv[j] + ti * cv[j]) * QS);
    }
    int p = (s & 8) | ((s & 7) ^ (r & 7));
    *(bf16x8*)&As_[r * 128 + p * 8] = o;
  }
  // stage B (K rows ct*128.., kv-head hk) with rope (no scale)
#pragma unroll
  for (int i = 0; i < 8; ++i) {
    int L = i * 256 + tid;
    int r = L >> 4, s = L & 15;
    int srow = ct * 128 + r;
    bf16x8 v = *(const bf16x8*)(C1 + (size_t)srow * 6144 + 4096 + hk * 128 + s * 8);
    f32x4v cv = *(const f32x4v*)&cosb[srow * 64 + s * 4];
    f32x4v sv = *(const f32x4v*)&sinb[srow * 64 + s * 4];
    bf16x8 o;
#pragma unroll
    for (int j = 0; j < 4; ++j) {
      float tr = bf2f((ushort_t)v[2 * j]);
      float ti = bf2f((ushort_t)v[2 * j + 1]);
      o[2 * j] = (short)f2bf(tr * cv[j] - ti * sv[j]);
      o[2 * j + 1] = (short)f2bf(tr * sv[j] + ti * cv[j]);
    }
    int p = (s & 8) | ((s & 7) ^ (r & 7));
    *(bf16x8*)&Bs_[r * 128 + p * 8] = o;
  }
  __syncthreads();

  f32x4 acc[4][4] = {};
  bf16x8 af[4][4], bfr[4][4];
#pragma unroll
  for (int m = 0; m < 4; ++m)
#pragma unroll
    for (int ks = 0; ks < 4; ++ks) {
      int row = wr * 64 + m * 16 + lr;
      int c = ks * 4 + lk;
      int sc = (c & 8) | ((c & 7) ^ (row & 7));
      af[m][ks] = *(const bf16x8*)((const char*)&As_[0] + row * 256 + sc * 16);
    }
#pragma unroll
  for (int n = 0; n < 4; ++n)
#pragma unroll
    for (int ks = 0; ks < 4; ++ks) {
      int row = wc * 64 + n * 16 + lr;
      int c = ks * 4 + lk;
      int sc = (c & 8) | ((c & 7) ^ (row & 7));
      bfr[n][ks] = *(const bf16x8*)((const char*)&Bs_[0] + row * 256 + sc * 16);
    }
#pragma unroll
  for (int m = 0; m < 4; ++m)
#pragma unroll
    for (int n = 0; n < 4; ++n)
#pragma unroll
      for (int ks = 0; ks < 4; ++ks)
        acc[m][n] = __builtin_amdgcn_mfma_f32_16x16x32_bf16(af[m][ks], bfr[n][ks],
                                                            acc[m][n], 0, 0, 0);

  ushort_t* Pt = P + ((size_t)h * 136 + (size_t)(rt * (rt + 1) / 2) + ct) * 16384;
  const bool diag = (rt == ct);
#pragma unroll
  for (int m = 0; m < 4; m++)
#pragma unroll
    for (int n = 0; n < 4; n++) {
      int row = wr * 64 + m * 16 + lk * 4;
      int col = wc * 64 + n * 16 + lr;
#pragma unroll
      for (int j = 0; j < 4; j++) {
        float v = exp2_hw(acc[m][n][j]);
        if (diag && col > row + j) v = 0.f;
        Pt[(row + j) * 128 + col] = f2bf(v);
      }
    }
}

// ---------- gemmPV v2: 1-phase/64-K counted pipeline (verified R21) ----------
__global__ __launch_bounds__(512) void gemmPV_kernel(const ushort_t* __restrict__ P,
                                                     const ushort_t* __restrict__ VT,
                                                     ushort_t* __restrict__ AO) {
  __shared__ ushort_t Pa[3][128 * 64];  // 48KB
  __shared__ ushort_t Vb[3][128 * 64];  // 48KB
  const int h = blockIdx.x, hk = h >> 2;
  const int rt = 15 - (int)blockIdx.y;
  const int tid = threadIdx.x, w = tid >> 6, lane = tid & 63;
  const int wr = w >> 2, wc = w & 3;
  const int lr = lane & 15, lk = lane >> 4;

  const ushort_t* Ph = P + ((size_t)h * 136 + (size_t)(rt * (rt + 1) / 2)) * 16384;
  const ushort_t* Vh = VT + (size_t)hk * 128 * 2048;

  auto stageP = [&](int t, int buf, int i) {
    int L = i * 512 + tid;          // 0..1023
    int r = L >> 3, sc = L & 7;
    load_lds16(Ph + (size_t)(t >> 1) * 16384 + (size_t)r * 128 + ((t & 1) << 6) +
                   (((sc ^ (r & 7))) << 3),
               (char*)&Pa[buf][0] + L * 16);
  };
  auto stageV = [&](int t, int buf, int i) {
    int L = i * 512 + tid;
    int r = L >> 3, sc = L & 7;
    load_lds16(Vh + (size_t)r * 2048 + (t << 6) + (((sc ^ (r & 7))) << 3),
               (char*)&Vb[buf][0] + L * 16);
  };
  auto stageTile = [&](int t, int buf) {  // 4 issues
    stageP(t, buf, 0); stageP(t, buf, 1);
    stageV(t, buf, 0); stageV(t, buf, 1);
  };

  f32x4 acc[4][2] = {};
  f32x4 sacc[4] = {};
  bf16x8 ones;
#pragma unroll
  for (int e = 0; e < 8; ++e) ones[e] = (short)0x3F80;  // bf16 1.0

  const int NT = (rt + 1) * 2;  // >= 2

  stageTile(0, 0);
  stageTile(1, 1);
  asm volatile("s_waitcnt vmcnt(4)" ::: "memory");  // tile0 landed
  __builtin_amdgcn_s_barrier();

  int cur = 0;
  for (int t = 0; t < NT; ++t) {
    const char* Ac = (const char*)&Pa[cur][0];
    const char* Bc = (const char*)&Vb[cur][0];
    const int nxt = (cur + 2 >= 3) ? cur - 1 : cur + 2;  // (t+2)%3
    const bool pf = (t + 2 < NT);

    bf16x8 af[4][2], bfr[2][2];
#pragma unroll
    for (int mm = 0; mm < 4; ++mm)
#pragma unroll
      for (int ks = 0; ks < 2; ++ks) {
        int row = wr * 64 + mm * 16 + lr;
        af[mm][ks] = *(const bf16x8*)(Ac + row * 128 + (((ks * 4 + lk) ^ (row & 7)) << 4));
      }
#pragma unroll
    for (int n = 0; n < 2; ++n)
#pragma unroll
      for (int ks = 0; ks < 2; ++ks) {
        int row = wc * 32 + n * 16 + lr;
        bfr[n][ks] = *(const bf16x8*)(Bc + row * 128 + (((ks * 4 + lk) ^ (row & 7)) << 4));
      }
    if (pf) stageTile(t + 2, nxt);
    __builtin_amdgcn_s_barrier();
    asm volatile("s_waitcnt lgkmcnt(0)" ::: "memory");
    __builtin_amdgcn_sched_barrier(0);
    __builtin_amdgcn_s_setprio(1);
#pragma unroll
    for (int mm = 0; mm < 4; ++mm) {
#pragma unroll
      for (int n = 0; n < 2; ++n)
#pragma unroll
        for (int ks = 0; ks < 2; ++ks)
          acc[mm][n] = __builtin_amdgcn_mfma_f32_16x16x32_bf16(af[mm][ks], bfr[n][ks],
                                                               acc[mm][n], 0, 0, 0);
#pragma unroll
      for (int ks = 0; ks < 2; ++ks)
        sacc[mm] = __builtin_amdgcn_mfma_f32_16x16x32_bf16(af[mm][ks], ones,
                                                           sacc[mm], 0, 0, 0);
    }
    __builtin_amdgcn_s_setprio(0);
    if (pf)
      asm volatile("s_waitcnt vmcnt(4)" ::: "memory");  // t+1 landed; t+2 in flight
    else if (t + 1 < NT)
      asm volatile("s_waitcnt vmcnt(0)" ::: "memory");  // tail drain
    __builtin_amdgcn_s_barrier();
    cur = (cur + 1 == 3) ? 0 : cur + 1;
  }
  // epilogue: O / rowsum -> AO
  const int q0 = rt * 128;
#pragma unroll
  for (int mm = 0; mm < 4; ++mm) {
    float invs[4];
#pragma unroll
    for (int j = 0; j < 4; ++j) invs[j] = 1.0f / sacc[mm][j];
#pragma unroll
    for (int n = 0; n < 2; ++n) {
      int row = wr * 64 + mm * 16 + lk * 4;
      int col = wc * 32 + n * 16 + lr;
#pragma unroll
      for (int j = 0; j < 4; ++j)
        AO[(size_t)(q0 + row + j) * 4096 + h * 128 + col] =
            f2bf(acc[mm][n][j] * invs[j]);
    }
  }
}

// ---------- flash attention (fallback when workspace too small) ----------
__global__ __launch_bounds__(256) void fattn_kernel(const ushort_t* __restrict__ C1,
                                                    const ushort_t* __restrict__ VT,
                                                    ushort_t* __restrict__ AO) {
  __shared__ ushort_t Pl[4][32][72];
  const int h = blockIdx.x, hk = h >> 2;
  const int qt = gridDim.y - 1 - blockIdx.y;
  const int tid = threadIdx.x, w = tid >> 6, lane = tid & 63;
  const int lq = lane & 31, hi = lane >> 5;
  const int qw0 = qt * 128 + w * 32;
  const int qabs = qw0 + lq;

  const ushort_t* Kb = C1 + 4096 + (size_t)hk * 128;
  const ushort_t* Vb = VT + (size_t)hk * 128 * 2048;

  bf16x8 qf[8];
  {
    const ushort_t* qrow = C1 + (size_t)qabs * 6144 + h * 128;
#pragma unroll
    for (int s = 0; s < 8; s++) qf[s] = *(const bf16x8*)(qrow + s * 16 + hi * 8);
  }
  f32x16 ot[4] = {};
  float mrow = -1e30f, ssum = 0.f;

  const int ktmax = (qw0 + 31) >> 6;
  for (int kt = 0; kt <= ktmax; kt++) {
    f32x16 sg[2] = {};
#pragma unroll
    for (int g = 0; g < 2; g++) {
      bf16x8 kfa[8];
      const ushort_t* krow = Kb + (size_t)(kt * 64 + g * 32 + lq) * 6144 + hi * 8;
#pragma unroll
      for (int s = 0; s < 8; s++) kfa[s] = *(const bf16x8*)(krow + s * 16);
#pragma unroll
      for (int s = 0; s < 8; s++)
        sg[g] = __builtin_amdgcn_mfma_f32_32x32x16_bf16(kfa[s], qf[s], sg[g], 0, 0, 0);
    }
    if (kt * 64 + 63 > qw0) {
#pragma unroll
      for (int g = 0; g < 2; g++)
#pragma unroll
        for (int r = 0; r < 16; r++) {
          int key = kt * 64 + g * 32 + (r & 3) + 8 * (r >> 2) + 4 * hi;
          if (key > qabs) sg[g][r] = -1e30f;
        }
    }
    float pm = -1e30f;
#pragma unroll
    for (int g = 0; g < 2; g++)
#pragma unroll
      for (int r = 0; r < 16; r++) pm = fmaxf(pm, sg[g][r]);
    pm = fmaxf(pm, __shfl_xor(pm, 32));
    float mnew = fmaxf(mrow, pm);
    float corr = exp2_hw(mrow - mnew);
    mrow = mnew;
    float ps = 0.f;
#pragma unroll
    for (int g = 0; g < 2; g++)
#pragma unroll
      for (int r = 0; r < 16; r++) {
        float e = exp2_hw(sg[g][r] - mnew);
        sg[g][r] = e;
        ps += e;
      }
    ps += __shfl_xor(ps, 32);
    ssum = ssum * corr + ps;
    if (!__all(corr == 1.f)) {
#pragma unroll
      for (int d = 0; d < 4; d++)
#pragma unroll
        for (int r = 0; r < 16; r++) ot[d][r] *= corr;
    }
#pragma unroll
    for (int g = 0; g < 2; g++)
#pragma unroll
      for (int rq = 0; rq < 4; rq++) {
        bf16x4 pk;
#pragma unroll
        for (int j = 0; j < 4; j++) pk[j] = (short)f2bf(sg[g][rq * 4 + j]);
        *(bf16x4*)&Pl[w][lq][g * 32 + rq * 8 + hi * 4] = pk;
      }
    asm volatile("s_waitcnt lgkmcnt(0)" ::: "memory");
    bf16x8 pf[4];
#pragma unroll
    for (int s = 0; s < 4; s++) pf[s] = *(const bf16x8*)&Pl[w][lq][s * 16 + hi * 8];
#pragma unroll
    for (int d = 0; d < 4; d++) {
      bf16x8 vfa[4];
      const ushort_t* vrow = Vb + (size_t)(d * 32 + lq) * 2048 + kt * 64 + hi * 8;
#pragma unroll
      for (int s = 0; s < 4; s++) vfa[s] = *(const bf16x8*)(vrow + s * 16);
#pragma unroll
      for (int s = 0; s < 4; s++)
        ot[d] = __builtin_amdgcn_mfma_f32_32x32x16_bf16(vfa[s], pf[s], ot[d], 0, 0, 0);
    }
  }
  const float inv = 1.0f / ssum;
  ushort_t* orow = AO + (size_t)qabs * 4096 + h * 128;
#pragma unroll
  for (int d = 0; d < 4; d++)
#pragma unroll
    for (int rq = 0; rq < 4; rq++) {
      bf16x4 ok;
#pragma unroll
      for (int j = 0; j < 4; j++) ok[j] = (short)f2bf(ot[d][rq * 4 + j] * inv);
      *(bf16x4*)(orow + d * 32 + rq * 8 + hi * 4) = ok;
    }
}

// ---------- launch ----------
extern "C" void kernel_launch(void* const* d_in, const int* in_sizes, int n_in,
                              void* d_out, int out_size, void* d_ws, size_t ws_size,
                              hipStream_t stream) {
  (void)in_sizes; (void)n_in; (void)out_size;
  const float* x    = (const float*)d_in[0];
  const float* wq   = (const float*)d_in[1];
  const float* wk   = (const float*)d_in[2];
  const float* wv   = (const float*)d_in[3];
  const float* wo   = (const float*)d_in[4];
  const float* cosb = (const float*)d_in[5];
  const float* sinb = (const float*)d_in[6];

  char* ws = (char*)d_ws;
  const bool fast = ws_size >= (215ull << 20);

  if (fast) {
    // layout (MiB): C1[0,24) VT[24,28) woT[28,60) xb[60,76) wT[76,124)
    //               P[60,196) (xb+wT dead after gemm1)  AO[196,212)
    ushort_t* C1  = (ushort_t*)(ws);
    ushort_t* VT  = (ushort_t*)(ws + ((size_t)24 << 20));
    ushort_t* woT = (ushort_t*)(ws + ((size_t)28 << 20));
    ushort_t* xb  = (ushort_t*)(ws + ((size_t)60 << 20));
    ushort_t* wT  = (ushort_t*)(ws + ((size_t)76 << 20));
    ushort_t* P   = (ushort_t*)(ws + ((size_t)60 << 20));
    ushort_t* AO  = (ushort_t*)(ws + ((size_t)196 << 20));

    // consolidated prep: cvt_x + all 4 weight transposes in ONE launch
    prepw_kernel<<<14336, 256, 0, stream>>>(x, wq, wk, wv, wo, xb, wT, woT);

    // QKV projection: 256x192 1-phase, grid 256, 2D-chunked XCD map
    gemmC_kernel<ushort_t><<<256, 512, 0, stream>>>(xb, wT, C1, 2048, 6144, 4096, 6144);

    // V -> VT only (rope now fused into gemmS staging)
    trv_kernel<<<dim3(16, 32), 256, 0, stream>>>(C1, VT);

    // QK^T with fused RoPE staging
    gemmS_kernel<<<dim3(136, 32), 256, 0, stream>>>(C1, P, cosb, sinb);
    gemmPV_kernel<<<dim3(32, 16), 512, 0, stream>>>(P, VT, AO);  // counted pipeline

    // output projection: 256x128 1-phase, grid 8x32 = 256, 2D-chunked XCD map
    gemmD_kernel<float><<<256, 512, 0, stream>>>(AO, woT, (float*)d_out, 2048, 4096, 4096, 4096);
  } else {
    // proven 92MiB layout + R7 fattn
    ushort_t* xb  = (ushort_t*)(ws);
    ushort_t* wT  = (ushort_t*)(ws + ((size_t)16 << 20));
    ushort_t* C1  = (ushort_t*)(ws + ((size_t)64 << 20));
    ushort_t* VT  = (ushort_t*)(ws + ((size_t)88 << 20));
    ushort_t* AO  = xb;
    ushort_t* woT = wT;

    cvt_x_kernel<<<4096, 256, 0, stream>>>(x, xb);
    tr_cvt_kernel<<<dim3(64, 64), 256, 0, stream>>>(wq, wT, 4096, 4096);
    tr_cvt_kernel<<<dim3(16, 64), 256, 0, stream>>>(wk, wT + (size_t)4096 * 4096, 4096, 1024);
    tr_cvt_kernel<<<dim3(16, 64), 256, 0, stream>>>(wv, wT + (size_t)5120 * 4096, 4096, 1024);
    gemm128_kernel<ushort_t><<<dim3(48, 16), 256, 0, stream>>>(xb, wT, C1, 2048, 6144, 4096, 6144);
    rope_kernel<<<5120, 256, 0, stream>>>(C1, cosb, sinb);
    trv_kernel<<<dim3(16, 32), 256, 0, stream>>>(C1, VT);
    tr_cvt_kernel<<<dim3(64, 64), 256, 0, stream>>>(wo, woT, 4096, 4096);
    fattn_kernel<<<dim3(32, 16), 256, 0, stream>>>(C1, VT, AO);
    gemm128_kernel<float><<<dim3(32, 16), 256, 0, stream>>>(AO, woT, (float*)d_out, 2048, 4096, 4096, 4096);
  }
}

// Round 25
// 319.966 us; speedup vs baseline: 1.0565x; 1.0565x over previous
//
#include <hip/hip_runtime.h>
#include <stdint.h>

typedef unsigned short ushort_t;
typedef short bf16x4 __attribute__((ext_vector_type(4)));
typedef short bf16x8 __attribute__((ext_vector_type(8)));
typedef float f32x4 __attribute__((ext_vector_type(4)));
typedef float f32x16 __attribute__((ext_vector_type(16)));
typedef float f32x4v __attribute__((ext_vector_type(4)));

// ---------- helpers ----------
__device__ __forceinline__ ushort_t f2bf(float f) {
  unsigned int u = __builtin_bit_cast(unsigned int, f);
  u += 0x7fffu + ((u >> 16) & 1u);
  return (ushort_t)(u >> 16);
}
__device__ __forceinline__ float bf2f(ushort_t h) {
  unsigned int u = ((unsigned int)h) << 16;
  return __builtin_bit_cast(float, u);
}
__device__ __forceinline__ float exp2_hw(float x) {
  return __builtin_amdgcn_exp2f(x);  // v_exp_f32: D = 2^S0
}
__device__ __forceinline__ void load_lds16(const void* g, void* l) {
  __builtin_amdgcn_global_load_lds(
      (const __attribute__((address_space(1))) void*)g,
      (__attribute__((address_space(3))) void*)l, 16, 0, 0);
}

// ---------- x fp32 -> bf16 (fallback path) ----------
__global__ __launch_bounds__(256) void cvt_x_kernel(const float* __restrict__ x,
                                                    ushort_t* __restrict__ xb) {
  int i = blockIdx.x * 256 + threadIdx.x;  // each thread: 8 elems
  const f32x4v* xv = (const f32x4v*)x;
  f32x4v a = xv[2 * i], b = xv[2 * i + 1];
  bf16x8 o;
  o[0] = (short)f2bf(a[0]); o[1] = (short)f2bf(a[1]);
  o[2] = (short)f2bf(a[2]); o[3] = (short)f2bf(a[3]);
  o[4] = (short)f2bf(b[0]); o[5] = (short)f2bf(b[1]);
  o[6] = (short)f2bf(b[2]); o[7] = (short)f2bf(b[3]);
  ((bf16x8*)xb)[i] = o;
}

// ---------- weight fp32 [R][C] -> bf16 transposed [C][R], vectorized (fallback) ----------
__global__ __launch_bounds__(256) void tr_cvt_kernel(const float* __restrict__ src,
                                                     ushort_t* __restrict__ dst,
                                                     int R, int C) {
  __shared__ float tile[64][65];
  int r0 = blockIdx.y * 64, c0 = blockIdx.x * 64;
  int t = threadIdx.x;
#pragma unroll
  for (int i = 0; i < 4; i++) {
    int idx = t + i * 256;          // 0..1023
    int r = idx >> 4, c4 = idx & 15;
    f32x4v v = *(const f32x4v*)&src[(size_t)(r0 + r) * C + c0 + c4 * 4];
#pragma unroll
    for (int j = 0; j < 4; j++) tile[r][c4 * 4 + j] = v[j];
  }
  __syncthreads();
#pragma unroll
  for (int i = 0; i < 4; i++) {
    int idx = t + i * 256;
    int cr = idx >> 4, cg = idx & 15;
    bf16x4 o;
#pragma unroll
    for (int j = 0; j < 4; j++) o[j] = (short)f2bf(tile[cg * 4 + j][cr]);
    *(bf16x4*)&dst[(size_t)(c0 + cr) * R + r0 + cg * 4] = o;
  }
}

// ---------- consolidated prep: cvt_x + 4 weight transposes (verified R23) ----------
__global__ __launch_bounds__(256) void prepw_kernel(const float* __restrict__ x,
                                                    const float* __restrict__ wq,
                                                    const float* __restrict__ wk,
                                                    const float* __restrict__ wv,
                                                    const float* __restrict__ wo,
                                                    ushort_t* __restrict__ xb,
                                                    ushort_t* __restrict__ wT,
                                                    ushort_t* __restrict__ woT) {
  __shared__ float tile[64][65];
  const int id = blockIdx.x;
  const int t = threadIdx.x;
  if (id < 4096) {
    int i = id * 256 + t;
    const f32x4v* xv = (const f32x4v*)x;
    f32x4v a = xv[2 * i], b = xv[2 * i + 1];
    bf16x8 o;
    o[0] = (short)f2bf(a[0]); o[1] = (short)f2bf(a[1]);
    o[2] = (short)f2bf(a[2]); o[3] = (short)f2bf(a[3]);
    o[4] = (short)f2bf(b[0]); o[5] = (short)f2bf(b[1]);
    o[6] = (short)f2bf(b[2]); o[7] = (short)f2bf(b[3]);
    ((bf16x8*)xb)[i] = o;
    return;
  }
  const float* src;
  ushort_t* dst;
  int C, r0, c0;
  if (id < 8192) {
    int q = id - 4096; src = wq; dst = wT; C = 4096;
    c0 = (q & 63) * 64; r0 = (q >> 6) * 64;
  } else if (id < 9216) {
    int q = id - 8192; src = wk; dst = wT + (size_t)4096 * 4096; C = 1024;
    c0 = (q & 15) * 64; r0 = (q >> 4) * 64;
  } else if (id < 10240) {
    int q = id - 9216; src = wv; dst = wT + (size_t)5120 * 4096; C = 1024;
    c0 = (q & 15) * 64; r0 = (q >> 4) * 64;
  } else {
    int q = id - 10240; src = wo; dst = woT; C = 4096;
    c0 = (q & 63) * 64; r0 = (q >> 6) * 64;
  }
  const int R = 4096;
#pragma unroll
  for (int i = 0; i < 4; i++) {
    int idx = t + i * 256;
    int r = idx >> 4, c4 = idx & 15;
    f32x4v v = *(const f32x4v*)&src[(size_t)(r0 + r) * C + c0 + c4 * 4];
#pragma unroll
    for (int j = 0; j < 4; j++) tile[r][c4 * 4 + j] = v[j];
  }
  __syncthreads();
#pragma unroll
  for (int i = 0; i < 4; i++) {
    int idx = t + i * 256;
    int cr = idx >> 4, cg = idx & 15;
    bf16x4 o;
#pragma unroll
    for (int j = 0; j < 4; j++) o[j] = (short)f2bf(tile[cg * 4 + j][cr]);
    *(bf16x4*)&dst[(size_t)(c0 + cr) * R + r0 + cg * 4] = o;
  }
}

// ---------- RoPE in-place on C1 (Q cols 0..4095 pre-scaled by scale*log2e) ----------
__global__ __launch_bounds__(256) void rope_kernel(ushort_t* __restrict__ C1,
                                                   const float* __restrict__ cosb,
                                                   const float* __restrict__ sinb) {
  int idx = blockIdx.x * 256 + threadIdx.x;  // 2048 * 640
  int s = idx / 640;
  int col0 = (idx % 640) * 8;
  int i0 = (col0 & 127) >> 1;
  const float qs = (col0 < 4096) ? 0.12753055296570565f : 1.0f;  // scale*log2e
  ushort_t* p = C1 + (size_t)s * 6144 + col0;
  bf16x8 v = *(const bf16x8*)p;
  bf16x8 o;
  const float* cr = cosb + s * 64 + i0;
  const float* sr = sinb + s * 64 + i0;
#pragma unroll
  for (int j = 0; j < 4; j++) {
    float tr = bf2f((ushort_t)v[2 * j]);
    float ti = bf2f((ushort_t)v[2 * j + 1]);
    float c = cr[j], sn = sr[j];
    o[2 * j] = (short)f2bf((tr * c - ti * sn) * qs);
    o[2 * j + 1] = (short)f2bf((tr * sn + ti * c) * qs);
  }
  *(bf16x8*)p = o;
}

// ---------- V part of C1 -> VT [1024][2048] (row = hk*128+d, col = s) ----------
__global__ __launch_bounds__(256) void trv_kernel(const ushort_t* __restrict__ C1,
                                                  ushort_t* __restrict__ VT) {
  __shared__ ushort_t tile[64][65];
  int c0 = blockIdx.x * 64;  // within 1024
  int r0 = blockIdx.y * 64;  // within 2048
  int t = threadIdx.x;
#pragma unroll
  for (int i = 0; i < 16; i++) {
    int idx = t + i * 256;
    int r = idx >> 6, c = idx & 63;
    tile[r][c] = C1[(size_t)(r0 + r) * 6144 + 5120 + c0 + c];
  }
  __syncthreads();
#pragma unroll
  for (int i = 0; i < 16; i++) {
    int idx = t + i * 256;
    int cr = idx >> 6, cc = idx & 63;
    VT[(size_t)(c0 + cr) * 2048 + r0 + cc] = tile[cc][cr];
  }
}

// ---------- consolidated prep2: rope + trv in one launch (verified R23) ----------
__global__ __launch_bounds__(256) void prep2_kernel(ushort_t* __restrict__ C1,
                                                    const float* __restrict__ cosb,
                                                    const float* __restrict__ sinb,
                                                    ushort_t* __restrict__ VT) {
  __shared__ ushort_t tile[64][65];
  const int id = blockIdx.x;
  const int t = threadIdx.x;
  if (id < 5120) {
    int idx = id * 256 + t;
    int s = idx / 640;
    int col0 = (idx % 640) * 8;
    int i0 = (col0 & 127) >> 1;
    const float qs = (col0 < 4096) ? 0.12753055296570565f : 1.0f;
    ushort_t* p = C1 + (size_t)s * 6144 + col0;
    bf16x8 v = *(const bf16x8*)p;
    bf16x8 o;
    const float* cr = cosb + s * 64 + i0;
    const float* sr = sinb + s * 64 + i0;
#pragma unroll
    for (int j = 0; j < 4; j++) {
      float tr = bf2f((ushort_t)v[2 * j]);
      float ti = bf2f((ushort_t)v[2 * j + 1]);
      float c = cr[j], sn = sr[j];
      o[2 * j] = (short)f2bf((tr * c - ti * sn) * qs);
      o[2 * j + 1] = (short)f2bf((tr * sn + ti * c) * qs);
    }
    *(bf16x8*)p = o;
    return;
  }
  int q = id - 5120;
  int c0 = (q & 15) * 64;  // within 1024
  int r0 = (q >> 4) * 64;  // within 2048
#pragma unroll
  for (int i = 0; i < 16; i++) {
    int idx = t + i * 256;
    int r = idx >> 6, c = idx & 63;
    tile[r][c] = C1[(size_t)(r0 + r) * 6144 + 5120 + c0 + c];
  }
  __syncthreads();
#pragma unroll
  for (int i = 0; i < 16; i++) {
    int idx = t + i * 256;
    int cr = idx >> 6, cc = idx & 63;
    VT[(size_t)(c0 + cr) * 2048 + r0 + cc] = tile[cc][cr];
  }
}

// ---------- 2D-chunked XCD block mapping ----------
__device__ __forceinline__ void xcd_chunk_map(int id, int nby, int nbx,
                                              int& browi, int& bcoli) {
  const int xcd = id & 7;
  const int j = id >> 3;
  const int rch = nby >> 1, cch = nbx >> 2;  // chunk dims
  const int cr = xcd >> 2, cc = xcd & 3;     // chunk grid is 2 x 4
  const int r = j / cch, c = j % cch;
  browi = cr * rch + r;
  bcoli = cc * cch + c;
}

// ---------- GEMM 256x192, 1-phase/64-K (gemm1/QKV; verified R22) ----------
template <typename OutT>
__global__ __launch_bounds__(512) void gemmC_kernel(const ushort_t* __restrict__ A,
                                                    const ushort_t* __restrict__ BT,
                                                    OutT* __restrict__ C,
                                                    int M, int N, int K, int ldc) {
  __shared__ ushort_t As[2][256 * 64];  // 64KB
  __shared__ ushort_t Bs[3][192 * 64];  // 72KB
  const int nbx = N / 192, nby = M >> 8;
  int browi, bcoli;
  xcd_chunk_map((int)blockIdx.x, nby, nbx, browi, bcoli);
  const int brow = browi << 8, bcol = bcoli * 192;
  const int tid = threadIdx.x, w = tid >> 6, lane = tid & 63;
  const int wr = w >> 2, wc = w & 3;
  const int lr = lane & 15, lk = lane >> 4;

  const ushort_t* Ab = A + (size_t)brow * K;
  const ushort_t* Bb = BT + (size_t)bcol * K;

  auto stageQ = [&](const ushort_t* gbase, char* lds, int t, int q) {
    int L = q * 512 + tid;
    int r = L >> 3, sc = L & 7;
    load_lds16(gbase + (size_t)r * K + (t << 6) + ((sc ^ (r & 7)) << 3), lds + L * 16);
  };

  f32x4 acc[8][3] = {};
  const int NT = K >> 6;  // requires NT >= 3

  // prologue: B(0)x3, A(0)q0,q2,q1,q3, B(1)x3; drain through A(0)q3 -> vmcnt(3)
#pragma unroll
  for (int q = 0; q < 3; ++q) stageQ(Bb, (char*)&Bs[0][0], 0, q);
  stageQ(Ab, (char*)&As[0][0], 0, 0);
  stageQ(Ab, (char*)&As[0][0], 0, 2);
  stageQ(Ab, (char*)&As[0][0], 0, 1);
  stageQ(Ab, (char*)&As[0][0], 0, 3);
#pragma unroll
  for (int q = 0; q < 3; ++q) stageQ(Bb, (char*)&Bs[1][0], 1, q);
  asm volatile("s_waitcnt vmcnt(3)" ::: "memory");
  __builtin_amdgcn_s_barrier();

  int bcur = 0;
  for (int t = 0; t < NT; ++t) {
    const int c = t & 1;
    const char* Ac = (const char*)&As[c][0];
    const char* Bc = (const char*)&Bs[bcur][0];
    char* An = (char*)&As[c ^ 1][0];
    const int bnxt = (bcur + 2 >= 3) ? bcur - 1 : bcur + 2;  // (t+2)%3
    char* Bn = (char*)&Bs[bnxt][0];
    const bool pfA = (t + 1 < NT), pfB = (t + 2 < NT);

    bf16x8 af[8][2], bfr[3][2];
#pragma unroll
    for (int mm = 0; mm < 8; ++mm)
#pragma unroll
      for (int ks = 0; ks < 2; ++ks) {
        int rA = wr * 128 + mm * 16 + lr;
        af[mm][ks] = *(const bf16x8*)(Ac + rA * 128 + (((ks * 4 + lk) ^ (rA & 7)) << 4));
      }
#pragma unroll
    for (int n = 0; n < 3; ++n)
#pragma unroll
      for (int ks = 0; ks < 2; ++ks) {
        int rB = wc * 48 + n * 16 + lr;
        bfr[n][ks] = *(const bf16x8*)(Bc + rB * 128 + (((ks * 4 + lk) ^ (rB & 7)) << 4));
      }
    if (pfA) {
      stageQ(Ab, An, t + 1, 0); stageQ(Ab, An, t + 1, 2);
      stageQ(Ab, An, t + 1, 1); stageQ(Ab, An, t + 1, 3);
    }
    if (pfB) { stageQ(Bb, Bn, t + 2, 0); stageQ(Bb, Bn, t + 2, 1); stageQ(Bb, Bn, t + 2, 2); }
    __builtin_amdgcn_s_barrier();
    asm volatile("s_waitcnt lgkmcnt(0)" ::: "memory");
    __builtin_amdgcn_sched_barrier(0);
    __builtin_amdgcn_s_setprio(1);
#pragma unroll
    for (int mm = 0; mm < 8; ++mm)
#pragma unroll
      for (int n = 0; n < 3; ++n)
#pragma unroll
        for (int ks = 0; ks < 2; ++ks)
          acc[mm][n] = __builtin_amdgcn_mfma_f32_16x16x32_bf16(af[mm][ks], bfr[n][ks],
                                                               acc[mm][n], 0, 0, 0);
    __builtin_amdgcn_s_setprio(0);
    if (pfB)
      asm volatile("s_waitcnt vmcnt(3)" ::: "memory");  // A(t+1)+B(t+1) landed
    else if (pfA)
      asm volatile("s_waitcnt vmcnt(0)" ::: "memory");  // tail drain
    __builtin_amdgcn_s_barrier();
    bcur = (bcur + 1 == 3) ? 0 : bcur + 1;
  }
  // epilogue
#pragma unroll
  for (int m = 0; m < 8; ++m)
#pragma unroll
    for (int n = 0; n < 3; ++n) {
      int row = brow + wr * 128 + m * 16 + lk * 4;
      int col = bcol + wc * 48 + n * 16 + lr;
#pragma unroll
      for (int j = 0; j < 4; ++j) {
        float v = acc[m][n][j];
        if constexpr (sizeof(OutT) == 2)
          C[(size_t)(row + j) * ldc + col] = (OutT)f2bf(v);
        else
          C[(size_t)(row + j) * ldc + col] = v;
      }
    }
}

// ---------- GEMM 256x128, 1-phase/64-K (gemm2; verified R22) ----------
template <typename OutT>
__global__ __launch_bounds__(512) void gemmD_kernel(const ushort_t* __restrict__ A,
                                                    const ushort_t* __restrict__ BT,
                                                    OutT* __restrict__ C,
                                                    int M, int N, int K, int ldc) {
  __shared__ ushort_t As[3][256 * 64];  // 96KB
  __shared__ ushort_t Bs[3][128 * 64];  // 48KB
  const int nbx = N >> 7, nby = M >> 8;
  int browi, bcoli;
  xcd_chunk_map((int)blockIdx.x, nby, nbx, browi, bcoli);
  const int brow = browi << 8, bcol = bcoli << 7;
  const int tid = threadIdx.x, w = tid >> 6, lane = tid & 63;
  const int wr = w >> 2, wc = w & 3;
  const int lr = lane & 15, lk = lane >> 4;

  const ushort_t* Ab = A + (size_t)brow * K;
  const ushort_t* Bb = BT + (size_t)bcol * K;

  auto stageQ = [&](const ushort_t* gbase, char* lds, int t, int q) {
    int L = q * 512 + tid;
    int r = L >> 3, sc = L & 7;
    load_lds16(gbase + (size_t)r * K + (t << 6) + ((sc ^ (r & 7)) << 3), lds + L * 16);
  };
  auto stageTile = [&](int t, int buf) {  // 6 loads: A q0..q3 + B q0,q1
#pragma unroll
    for (int q = 0; q < 4; ++q) stageQ(Ab, (char*)&As[buf][0], t, q);
#pragma unroll
    for (int q = 0; q < 2; ++q) stageQ(Bb, (char*)&Bs[buf][0], t, q);
  };

  f32x4 acc[8][2] = {};
  const int NT = K >> 6;

  stageTile(0, 0);
  stageTile(1, 1);
  asm volatile("s_waitcnt vmcnt(6)" ::: "memory");
  __builtin_amdgcn_s_barrier();

  int cur = 0;
  for (int t = 0; t < NT; ++t) {
    const char* Ac = (const char*)&As[cur][0];
    const char* Bc = (const char*)&Bs[cur][0];
    const int nxt = (cur + 2 >= 3) ? cur - 1 : cur + 2;  // (t+2)%3
    const bool pf = (t + 2 < NT);

    bf16x8 af[8][2], bfr[2][2];
#pragma unroll
    for (int mm = 0; mm < 8; ++mm)
#pragma unroll
      for (int ks = 0; ks < 2; ++ks) {
        int rA = wr * 128 + mm * 16 + lr;
        af[mm][ks] = *(const bf16x8*)(Ac + rA * 128 + (((ks * 4 + lk) ^ (rA & 7)) << 4));
      }
#pragma unroll
    for (int n = 0; n < 2; ++n)
#pragma unroll
      for (int ks = 0; ks < 2; ++ks) {
        int rB = wc * 32 + n * 16 + lr;
        bfr[n][ks] = *(const bf16x8*)(Bc + rB * 128 + (((ks * 4 + lk) ^ (rB & 7)) << 4));
      }
    if (pf) stageTile(t + 2, nxt);
    __builtin_amdgcn_s_barrier();
    asm volatile("s_waitcnt lgkmcnt(0)" ::: "memory");
    __builtin_amdgcn_sched_barrier(0);
    __builtin_amdgcn_s_setprio(1);
#pragma unroll
    for (int mm = 0; mm < 8; ++mm)
#pragma unroll
      for (int n = 0; n < 2; ++n)
#pragma unroll
        for (int ks = 0; ks < 2; ++ks)
          acc[mm][n] = __builtin_amdgcn_mfma_f32_16x16x32_bf16(af[mm][ks], bfr[n][ks],
                                                               acc[mm][n], 0, 0, 0);
    __builtin_amdgcn_s_setprio(0);
    if (pf)
      asm volatile("s_waitcnt vmcnt(6)" ::: "memory");  // t+1 landed; t+2 in flight
    else if (t + 1 < NT)
      asm volatile("s_waitcnt vmcnt(0)" ::: "memory");  // tail drain
    __builtin_amdgcn_s_barrier();
    cur = (cur == 2) ? 0 : cur + 1;
  }
  // epilogue
#pragma unroll
  for (int m = 0; m < 8; ++m)
#pragma unroll
    for (int n = 0; n < 2; ++n) {
      int row = brow + wr * 128 + m * 16 + lk * 4;
      int col = bcol + wc * 32 + n * 16 + lr;
#pragma unroll
      for (int j = 0; j < 4; ++j) {
        float v = acc[m][n][j];
        if constexpr (sizeof(OutT) == 2)
          C[(size_t)(row + j) * ldc + col] = (OutT)f2bf(v);
        else
          C[(size_t)(row + j) * ldc + col] = v;
      }
    }
}

// ---------- GEMM: C[M][ldc] = A[M][K] * BT[N][K]^T  (m97 structure, fallback) ----------
template <typename OutT>
__global__ __launch_bounds__(256) void gemm128_kernel(const ushort_t* __restrict__ A,
                                                      const ushort_t* __restrict__ BT,
                                                      OutT* __restrict__ C,
                                                      int M, int N, int K, int ldc) {
  __shared__ ushort_t As[128 * 32];
  __shared__ ushort_t Bs[128 * 32];
  int brow = blockIdx.y * 128, bcol = blockIdx.x * 128;
  int tid = threadIdx.x, w = tid >> 6, lane = tid & 63;
  int wr = w >> 1, wc = w & 1;
  int lr = lane & 15, lk = lane >> 4;
  f32x4 acc[4][4] = {};

  int srow = lane >> 2;
  int scol = (lane & 3) * 8;
  const ushort_t* Ab = A + (size_t)brow * K + scol;
  const ushort_t* Bb = BT + (size_t)bcol * K + scol;

  for (int kt = 0; kt < K; kt += 32) {
#pragma unroll
    for (int i = 0; i < 2; i++) {
      int seg = w * 2 + i;
      int row = seg * 16 + srow;
      load_lds16(Ab + (size_t)row * K + kt, (char*)As + seg * 1024);
      load_lds16(Bb + (size_t)row * K + kt, (char*)Bs + seg * 1024);
    }
    __syncthreads();
    bf16x8 af[4], bfr[4];
#pragma unroll
    for (int m = 0; m < 4; m++)
      af[m] = *(const bf16x8*)&As[(wr * 64 + m * 16 + lr) * 32 + lk * 8];
#pragma unroll
    for (int n = 0; n < 4; n++)
      bfr[n] = *(const bf16x8*)&Bs[(wc * 64 + n * 16 + lr) * 32 + lk * 8];
#pragma unroll
    for (int m = 0; m < 4; m++)
#pragma unroll
      for (int n = 0; n < 4; n++)
        acc[m][n] = __builtin_amdgcn_mfma_f32_16x16x32_bf16(af[m], bfr[n], acc[m][n], 0, 0, 0);
    __syncthreads();
  }
#pragma unroll
  for (int m = 0; m < 4; m++)
#pragma unroll
    for (int n = 0; n < 4; n++) {
      int row = brow + wr * 64 + m * 16 + lk * 4;
      int col = bcol + wc * 64 + n * 16 + lr;
#pragma unroll
      for (int j = 0; j < 4; j++) {
        float v = acc[m][n][j];
        if constexpr (sizeof(OutT) == 2)
          C[(size_t)(row + j) * ldc + col] = (OutT)f2bf(v);
        else
          C[(size_t)(row + j) * ldc + col] = v;
      }
    }
}

// ---------- gemmS: P[tile] = exp2(Q K^T) causal, single-stage K=128 (verified R20) ----------
__global__ __launch_bounds__(256) void gemmS_kernel(const ushort_t* __restrict__ C1,
                                                    ushort_t* __restrict__ P) {
  int rem = blockIdx.x, rt = 0;
  while (rem > rt) { rem -= (rt + 1); rt++; }
  const int ct = rem;
  const int h = blockIdx.y, hk = h >> 2;

  __shared__ ushort_t As_[128 * 128];  // 32KB
  __shared__ ushort_t Bs_[128 * 128];  // 32KB
  const int tid = threadIdx.x, w = tid >> 6, lane = tid & 63;
  const int wr = w >> 1, wc = w & 1;
  const int lr = lane & 15, lk = lane >> 4;

  const ushort_t* Ag = C1 + (size_t)(rt * 128) * 6144 + h * 128;          // Q rows
  const ushort_t* Bg = C1 + (size_t)(ct * 128) * 6144 + 4096 + hk * 128;  // K rows

#pragma unroll
  for (int i = 0; i < 8; ++i) {
    int L = i * 256 + tid;
    int r = L >> 4, s = L & 15;
    int g = (s & 8) | ((s & 7) ^ (r & 7));
    load_lds16(Ag + (size_t)r * 6144 + g * 8, (char*)&As_[0] + L * 16);
  }
#pragma unroll
  for (int i = 0; i < 8; ++i) {
    int L = i * 256 + tid;
    int r = L >> 4, s = L & 15;
    int g = (s & 8) | ((s & 7) ^ (r & 7));
    load_lds16(Bg + (size_t)r * 6144 + g * 8, (char*)&Bs_[0] + L * 16);
  }
  asm volatile("s_waitcnt vmcnt(0)" ::: "memory");
  __builtin_amdgcn_s_barrier();

  f32x4 acc[4][4] = {};
  bf16x8 af[4][4], bfr[4][4];
#pragma unroll
  for (int m = 0; m < 4; ++m)
#pragma unroll
    for (int ks = 0; ks < 4; ++ks) {
      int row = wr * 64 + m * 16 + lr;
      int c = ks * 4 + lk;
      int sc = (c & 8) | ((c & 7) ^ (row & 7));
      af[m][ks] = *(const bf16x8*)((const char*)&As_[0] + row * 256 + sc * 16);
    }
#pragma unroll
  for (int n = 0; n < 4; ++n)
#pragma unroll
    for (int ks = 0; ks < 4; ++ks) {
      int row = wc * 64 + n * 16 + lr;
      int c = ks * 4 + lk;
      int sc = (c & 8) | ((c & 7) ^ (row & 7));
      bfr[n][ks] = *(const bf16x8*)((const char*)&Bs_[0] + row * 256 + sc * 16);
    }
#pragma unroll
  for (int m = 0; m < 4; ++m)
#pragma unroll
    for (int n = 0; n < 4; ++n)
#pragma unroll
      for (int ks = 0; ks < 4; ++ks)
        acc[m][n] = __builtin_amdgcn_mfma_f32_16x16x32_bf16(af[m][ks], bfr[n][ks],
                                                            acc[m][n], 0, 0, 0);

  ushort_t* Pt = P + ((size_t)h * 136 + (size_t)(rt * (rt + 1) / 2) + ct) * 16384;
  const bool diag = (rt == ct);
#pragma unroll
  for (int m = 0; m < 4; m++)
#pragma unroll
    for (int n = 0; n < 4; n++) {
      int row = wr * 64 + m * 16 + lk * 4;
      int col = wc * 64 + n * 16 + lr;
#pragma unroll
      for (int j = 0; j < 4; j++) {
        float v = exp2_hw(acc[m][n][j]);
        if (diag && col > row + j) v = 0.f;
        Pt[(row + j) * 128 + col] = f2bf(v);
      }
    }
}

// ---------- gemmPV v2: 1-phase/64-K counted pipeline (verified R21) ----------
__global__ __launch_bounds__(512) void gemmPV_kernel(const ushort_t* __restrict__ P,
                                                     const ushort_t* __restrict__ VT,
                                                     ushort_t* __restrict__ AO) {
  __shared__ ushort_t Pa[3][128 * 64];  // 48KB
  __shared__ ushort_t Vb[3][128 * 64];  // 48KB
  const int h = blockIdx.x, hk = h >> 2;
  const int rt = 15 - (int)blockIdx.y;
  const int tid = threadIdx.x, w = tid >> 6, lane = tid & 63;
  const int wr = w >> 2, wc = w & 3;
  const int lr = lane & 15, lk = lane >> 4;

  const ushort_t* Ph = P + ((size_t)h * 136 + (size_t)(rt * (rt + 1) / 2)) * 16384;
  const ushort_t* Vh = VT + (size_t)hk * 128 * 2048;

  auto stageP = [&](int t, int buf, int i) {
    int L = i * 512 + tid;          // 0..1023
    int r = L >> 3, sc = L & 7;
    load_lds16(Ph + (size_t)(t >> 1) * 16384 + (size_t)r * 128 + ((t & 1) << 6) +
                   (((sc ^ (r & 7))) << 3),
               (char*)&Pa[buf][0] + L * 16);
  };
  auto stageV = [&](int t, int buf, int i) {
    int L = i * 512 + tid;
    int r = L >> 3, sc = L & 7;
    load_lds16(Vh + (size_t)r * 2048 + (t << 6) + (((sc ^ (r & 7))) << 3),
               (char*)&Vb[buf][0] + L * 16);
  };
  auto stageTile = [&](int t, int buf) {  // 4 issues
    stageP(t, buf, 0); stageP(t, buf, 1);
    stageV(t, buf, 0); stageV(t, buf, 1);
  };

  f32x4 acc[4][2] = {};
  f32x4 sacc[4] = {};
  bf16x8 ones;
#pragma unroll
  for (int e = 0; e < 8; ++e) ones[e] = (short)0x3F80;  // bf16 1.0

  const int NT = (rt + 1) * 2;  // >= 2

  stageTile(0, 0);
  stageTile(1, 1);
  asm volatile("s_waitcnt vmcnt(4)" ::: "memory");  // tile0 landed
  __builtin_amdgcn_s_barrier();

  int cur = 0;
  for (int t = 0; t < NT; ++t) {
    const char* Ac = (const char*)&Pa[cur][0];
    const char* Bc = (const char*)&Vb[cur][0];
    const int nxt = (cur + 2 >= 3) ? cur - 1 : cur + 2;  // (t+2)%3
    const bool pf = (t + 2 < NT);

    bf16x8 af[4][2], bfr[2][2];
#pragma unroll
    for (int mm = 0; mm < 4; ++mm)
#pragma unroll
      for (int ks = 0; ks < 2; ++ks) {
        int row = wr * 64 + mm * 16 + lr;
        af[mm][ks] = *(const bf16x8*)(Ac + row * 128 + (((ks * 4 + lk) ^ (row & 7)) << 4));
      }
#pragma unroll
    for (int n = 0; n < 2; ++n)
#pragma unroll
      for (int ks = 0; ks < 2; ++ks) {
        int row = wc * 32 + n * 16 + lr;
        bfr[n][ks] = *(const bf16x8*)(Bc + row * 128 + (((ks * 4 + lk) ^ (row & 7)) << 4));
      }
    if (pf) stageTile(t + 2, nxt);
    __builtin_amdgcn_s_barrier();
    asm volatile("s_waitcnt lgkmcnt(0)" ::: "memory");
    __builtin_amdgcn_sched_barrier(0);
    __builtin_amdgcn_s_setprio(1);
#pragma unroll
    for (int mm = 0; mm < 4; ++mm) {
#pragma unroll
      for (int n = 0; n < 2; ++n)
#pragma unroll
        for (int ks = 0; ks < 2; ++ks)
          acc[mm][n] = __builtin_amdgcn_mfma_f32_16x16x32_bf16(af[mm][ks], bfr[n][ks],
                                                               acc[mm][n], 0, 0, 0);
#pragma unroll
      for (int ks = 0; ks < 2; ++ks)
        sacc[mm] = __builtin_amdgcn_mfma_f32_16x16x32_bf16(af[mm][ks], ones,
                                                           sacc[mm], 0, 0, 0);
    }
    __builtin_amdgcn_s_setprio(0);
    if (pf)
      asm volatile("s_waitcnt vmcnt(4)" ::: "memory");  // t+1 landed; t+2 in flight
    else if (t + 1 < NT)
      asm volatile("s_waitcnt vmcnt(0)" ::: "memory");  // tail drain
    __builtin_amdgcn_s_barrier();
    cur = (cur + 1 == 3) ? 0 : cur + 1;
  }
  // epilogue: O / rowsum -> AO
  const int q0 = rt * 128;
#pragma unroll
  for (int mm = 0; mm < 4; ++mm) {
    float invs[4];
#pragma unroll
    for (int j = 0; j < 4; ++j) invs[j] = 1.0f / sacc[mm][j];
#pragma unroll
    for (int n = 0; n < 2; ++n) {
      int row = wr * 64 + mm * 16 + lk * 4;
      int col = wc * 32 + n * 16 + lr;
#pragma unroll
      for (int j = 0; j < 4; ++j)
        AO[(size_t)(q0 + row + j) * 4096 + h * 128 + col] =
            f2bf(acc[mm][n][j] * invs[j]);
    }
  }
}

// ---------- flash attention (fallback when workspace too small) ----------
__global__ __launch_bounds__(256) void fattn_kernel(const ushort_t* __restrict__ C1,
                                                    const ushort_t* __restrict__ VT,
                                                    ushort_t* __restrict__ AO) {
  __shared__ ushort_t Pl[4][32][72];
  const int h = blockIdx.x, hk = h >> 2;
  const int qt = gridDim.y - 1 - blockIdx.y;
  const int tid = threadIdx.x, w = tid >> 6, lane = tid & 63;
  const int lq = lane & 31, hi = lane >> 5;
  const int qw0 = qt * 128 + w * 32;
  const int qabs = qw0 + lq;

  const ushort_t* Kb = C1 + 4096 + (size_t)hk * 128;
  const ushort_t* Vb = VT + (size_t)hk * 128 * 2048;

  bf16x8 qf[8];
  {
    const ushort_t* qrow = C1 + (size_t)qabs * 6144 + h * 128;
#pragma unroll
    for (int s = 0; s < 8; s++) qf[s] = *(const bf16x8*)(qrow + s * 16 + hi * 8);
  }
  f32x16 ot[4] = {};
  float mrow = -1e30f, ssum = 0.f;

  const int ktmax = (qw0 + 31) >> 6;
  for (int kt = 0; kt <= ktmax; kt++) {
    f32x16 sg[2] = {};
#pragma unroll
    for (int g = 0; g < 2; g++) {
      bf16x8 kfa[8];
      const ushort_t* krow = Kb + (size_t)(kt * 64 + g * 32 + lq) * 6144 + hi * 8;
#pragma unroll
      for (int s = 0; s < 8; s++) kfa[s] = *(const bf16x8*)(krow + s * 16);
#pragma unroll
      for (int s = 0; s < 8; s++)
        sg[g] = __builtin_amdgcn_mfma_f32_32x32x16_bf16(kfa[s], qf[s], sg[g], 0, 0, 0);
    }
    if (kt * 64 + 63 > qw0) {
#pragma unroll
      for (int g = 0; g < 2; g++)
#pragma unroll
        for (int r = 0; r < 16; r++) {
          int key = kt * 64 + g * 32 + (r & 3) + 8 * (r >> 2) + 4 * hi;
          if (key > qabs) sg[g][r] = -1e30f;
        }
    }
    float pm = -1e30f;
#pragma unroll
    for (int g = 0; g < 2; g++)
#pragma unroll
      for (int r = 0; r < 16; r++) pm = fmaxf(pm, sg[g][r]);
    pm = fmaxf(pm, __shfl_xor(pm, 32));
    float mnew = fmaxf(mrow, pm);
    float corr = exp2_hw(mrow - mnew);
    mrow = mnew;
    float ps = 0.f;
#pragma unroll
    for (int g = 0; g < 2; g++)
#pragma unroll
      for (int r = 0; r < 16; r++) {
        float e = exp2_hw(sg[g][r] - mnew);
        sg[g][r] = e;
        ps += e;
      }
    ps += __shfl_xor(ps, 32);
    ssum = ssum * corr + ps;
    if (!__all(corr == 1.f)) {
#pragma unroll
      for (int d = 0; d < 4; d++)
#pragma unroll
        for (int r = 0; r < 16; r++) ot[d][r] *= corr;
    }
#pragma unroll
    for (int g = 0; g < 2; g++)
#pragma unroll
      for (int rq = 0; rq < 4; rq++) {
        bf16x4 pk;
#pragma unroll
        for (int j = 0; j < 4; j++) pk[j] = (short)f2bf(sg[g][rq * 4 + j]);
        *(bf16x4*)&Pl[w][lq][g * 32 + rq * 8 + hi * 4] = pk;
      }
    asm volatile("s_waitcnt lgkmcnt(0)" ::: "memory");
    bf16x8 pf[4];
#pragma unroll
    for (int s = 0; s < 4; s++) pf[s] = *(const bf16x8*)&Pl[w][lq][s * 16 + hi * 8];
#pragma unroll
    for (int d = 0; d < 4; d++) {
      bf16x8 vfa[4];
      const ushort_t* vrow = Vb + (size_t)(d * 32 + lq) * 2048 + kt * 64 + hi * 8;
#pragma unroll
      for (int s = 0; s < 4; s++) vfa[s] = *(const bf16x8*)(vrow + s * 16);
#pragma unroll
      for (int s = 0; s < 4; s++)
        ot[d] = __builtin_amdgcn_mfma_f32_32x32x16_bf16(vfa[s], pf[s], ot[d], 0, 0, 0);
    }
  }
  const float inv = 1.0f / ssum;
  ushort_t* orow = AO + (size_t)qabs * 4096 + h * 128;
#pragma unroll
  for (int d = 0; d < 4; d++)
#pragma unroll
    for (int rq = 0; rq < 4; rq++) {
      bf16x4 ok;
#pragma unroll
      for (int j = 0; j < 4; j++) ok[j] = (short)f2bf(ot[d][rq * 4 + j] * inv);
      *(bf16x4*)(orow + d * 32 + rq * 8 + hi * 4) = ok;
    }
}

// ---------- launch ----------
extern "C" void kernel_launch(void* const* d_in, const int* in_sizes, int n_in,
                              void* d_out, int out_size, void* d_ws, size_t ws_size,
                              hipStream_t stream) {
  (void)in_sizes; (void)n_in; (void)out_size;
  const float* x    = (const float*)d_in[0];
  const float* wq   = (const float*)d_in[1];
  const float* wk   = (const float*)d_in[2];
  const float* wv   = (const float*)d_in[3];
  const float* wo   = (const float*)d_in[4];
  const float* cosb = (const float*)d_in[5];
  const float* sinb = (const float*)d_in[6];

  char* ws = (char*)d_ws;
  const bool fast = ws_size >= (215ull << 20);

  if (fast) {
    // layout (MiB): C1[0,24) VT[24,28) woT[28,60) xb[60,76) wT[76,124)
    //               P[60,196) (xb+wT dead after gemm1)  AO[196,212)
    ushort_t* C1  = (ushort_t*)(ws);
    ushort_t* VT  = (ushort_t*)(ws + ((size_t)24 << 20));
    ushort_t* woT = (ushort_t*)(ws + ((size_t)28 << 20));
    ushort_t* xb  = (ushort_t*)(ws + ((size_t)60 << 20));
    ushort_t* wT  = (ushort_t*)(ws + ((size_t)76 << 20));
    ushort_t* P   = (ushort_t*)(ws + ((size_t)60 << 20));
    ushort_t* AO  = (ushort_t*)(ws + ((size_t)196 << 20));

    // consolidated prep: cvt_x + all 4 weight transposes in ONE launch
    prepw_kernel<<<14336, 256, 0, stream>>>(x, wq, wk, wv, wo, xb, wT, woT);

    // QKV projection: 256x192 1-phase, grid 256, 2D-chunked XCD map
    gemmC_kernel<ushort_t><<<256, 512, 0, stream>>>(xb, wT, C1, 2048, 6144, 4096, 6144);

    // consolidated rope + trv in ONE launch
    prep2_kernel<<<5632, 256, 0, stream>>>(C1, cosb, sinb, VT);

    gemmS_kernel<<<dim3(136, 32), 256, 0, stream>>>(C1, P);
    gemmPV_kernel<<<dim3(32, 16), 512, 0, stream>>>(P, VT, AO);  // counted pipeline

    // output projection: 256x128 1-phase, grid 8x32 = 256, 2D-chunked XCD map
    gemmD_kernel<float><<<256, 512, 0, stream>>>(AO, woT, (float*)d_out, 2048, 4096, 4096, 4096);
  } else {
    // proven 92MiB layout + R7 fattn
    ushort_t* xb  = (ushort_t*)(ws);
    ushort_t* wT  = (ushort_t*)(ws + ((size_t)16 << 20));
    ushort_t* C1  = (ushort_t*)(ws + ((size_t)64 << 20));
    ushort_t* VT  = (ushort_t*)(ws + ((size_t)88 << 20));
    ushort_t* AO  = xb;
    ushort_t* woT = wT;

    cvt_x_kernel<<<4096, 256, 0, stream>>>(x, xb);
    tr_cvt_kernel<<<dim3(64, 64), 256, 0, stream>>>(wq, wT, 4096, 4096);
    tr_cvt_kernel<<<dim3(16, 64), 256, 0, stream>>>(wk, wT + (size_t)4096 * 4096, 4096, 1024);
    tr_cvt_kernel<<<dim3(16, 64), 256, 0, stream>>>(wv, wT + (size_t)5120 * 4096, 4096, 1024);
    gemm128_kernel<ushort_t><<<dim3(48, 16), 256, 0, stream>>>(xb, wT, C1, 2048, 6144, 4096, 6144);
    rope_kernel<<<5120, 256, 0, stream>>>(C1, cosb, sinb);
    trv_kernel<<<dim3(16, 32), 256, 0, stream>>>(C1, VT);
    tr_cvt_kernel<<<dim3(64, 64), 256, 0, stream>>>(wo, woT, 4096, 4096);
    fattn_kernel<<<dim3(32, 16), 256, 0, stream>>>(C1, VT, AO);
    gemm128_kernel<float><<<dim3(32, 16), 256, 0, stream>>>(AO, woT, (float*)d_out, 2048, 4096, 4096, 4096);
  }
}